// Round 1
// baseline (213.037 us; speedup 1.0000x reference)
//
#include <hip/hip_runtime.h>

#define OC 128
#define V_SZ 30000
#define KW 5
#define L_IN 2560        // 40*64
#define L_OUT (L_IN - KW + 1)  // 2556
#define NB 32            // batch
#define TCO 4            // TC-1 outputs per batch

#define K_ROW (V_SZ * KW)          // 150000 floats per oc row
#define KELEMS (OC * V_SZ * KW)    // 19,200,000 floats

// ---------------------------------------------------------------------------
// Kernel A: transpose K[oc][v*5+w] -> Kt[v][w][oc]
// Tile: 16 consecutive i (= v*5+w) x all 128 oc. Block 256 threads.
// Phase 1: float4-coalesced reads (16 rows x 64B per wave), LDS store [ii][oc].
// Phase 2: float4-coalesced writes (512B contiguous per (v,w)).
// ---------------------------------------------------------------------------
__global__ __launch_bounds__(256) void transpose_k(const float* __restrict__ K,
                                                   float* __restrict__ Kt) {
    __shared__ float lds[16 * 132];   // [ii][oc], pad 132 to dodge bank conflicts
    const int i0  = blockIdx.x * 16;
    const int tid = threadIdx.x;

    // Phase 1: read. 2 passes of 64 oc-rows; each lane reads a float4 (4 i's).
    {
        const int ii4 = (tid & 3) * 4;      // 0,4,8,12
        #pragma unroll
        for (int r = 0; r < 2; ++r) {
            const int oc = r * 64 + (tid >> 2);
            const float4 kv = *reinterpret_cast<const float4*>(
                &K[(size_t)oc * K_ROW + i0 + ii4]);
            lds[(ii4 + 0) * 132 + oc] = kv.x;
            lds[(ii4 + 1) * 132 + oc] = kv.y;
            lds[(ii4 + 2) * 132 + oc] = kv.z;
            lds[(ii4 + 3) * 132 + oc] = kv.w;
        }
    }
    __syncthreads();

    // Phase 2: write. 2 passes; lane covers 4 oc (float4), 8 i's per pass.
    {
        const int oc4 = (tid & 31) * 4;
        #pragma unroll
        for (int r = 0; r < 2; ++r) {
            const int i_loc = r * 8 + (tid >> 5);
            const int i = i0 + i_loc;
            const int v = i / 5;
            const int w = i - v * 5;
            const float4 kv = *reinterpret_cast<const float4*>(&lds[i_loc * 132 + oc4]);
            *reinterpret_cast<float4*>(&Kt[(size_t)v * (KW * OC) + w * OC + oc4]) = kv;
        }
    }
}

// ---------------------------------------------------------------------------
// Kernel B: conv + relu + max-pool using transposed Kt.
// Grid: (ceil(L_OUT/64), NB). Block 256 = 8 l-groups x 32 lanes.
// Each lane owns 4 oc via float4; 5 coalesced float4 loads per output l.
// Running max starts at 0 => relu folded in. atomicMax on int view (vals >= 0).
// ---------------------------------------------------------------------------
__global__ __launch_bounds__(256) void conv_max(const int* __restrict__ tokens,
                                                const float* __restrict__ Kt,
                                                int* __restrict__ pooled) {
    const int b   = blockIdx.y;
    const int l0  = blockIdx.x * 64;
    const int tid = threadIdx.x;

    __shared__ int ids[64 + KW - 1];  // 68
    if (tid < 64 + KW - 1) {
        const int l = l0 + tid;
        ids[tid] = (l < L_IN) ? tokens[b * L_IN + l] : 0;
    }
    __syncthreads();

    const int grp = tid >> 5;         // 0..7  (l sub-index)
    const int oc4 = (tid & 31) * 4;   // 0..124

    float4 m = make_float4(0.f, 0.f, 0.f, 0.f);

    #pragma unroll 2
    for (int u = 0; u < 8; ++u) {
        const int li = u * 8 + grp;   // 0..63
        const int l  = l0 + li;
        if (l < L_OUT) {
            float4 s = make_float4(0.f, 0.f, 0.f, 0.f);
            #pragma unroll
            for (int w = 0; w < KW; ++w) {
                const int id = ids[li + w];
                const float4 kv = *reinterpret_cast<const float4*>(
                    &Kt[(size_t)id * (KW * OC) + w * OC + oc4]);
                s.x += kv.x; s.y += kv.y; s.z += kv.z; s.w += kv.w;
            }
            m.x = fmaxf(m.x, s.x);
            m.y = fmaxf(m.y, s.y);
            m.z = fmaxf(m.z, s.z);
            m.w = fmaxf(m.w, s.w);
        }
    }

    int* p = &pooled[b * OC + oc4];
    atomicMax(&p[0], __float_as_int(m.x));
    atomicMax(&p[1], __float_as_int(m.y));
    atomicMax(&p[2], __float_as_int(m.z));
    atomicMax(&p[3], __float_as_int(m.w));
}

// ---------------------------------------------------------------------------
// Kernel B-fallback: same as B but gathers from the ORIGINAL K layout
// (used only if ws can't hold the 76.8 MB transposed copy).
// ---------------------------------------------------------------------------
__global__ __launch_bounds__(256) void conv_max_fallback(const int* __restrict__ tokens,
                                                         const float* __restrict__ K,
                                                         int* __restrict__ pooled) {
    const int b   = blockIdx.y;
    const int l0  = blockIdx.x * 64;
    const int tid = threadIdx.x;

    __shared__ int ids[64 + KW - 1];
    if (tid < 64 + KW - 1) {
        const int l = l0 + tid;
        ids[tid] = (l < L_IN) ? tokens[b * L_IN + l] : 0;
    }
    __syncthreads();

    const int oc   = tid & 127;
    const int half = tid >> 7;   // 0..1
    float m = 0.f;

    for (int u = 0; u < 32; ++u) {
        const int li = u * 2 + half;
        const int l  = l0 + li;
        if (l < L_OUT) {
            float s = 0.f;
            #pragma unroll
            for (int w = 0; w < KW; ++w) {
                s += K[(size_t)oc * K_ROW + ids[li + w] * KW + w];
            }
            m = fmaxf(m, s);
        }
    }
    atomicMax(&pooled[b * OC + oc], __float_as_int(m));
}

// ---------------------------------------------------------------------------
// Kernel C: out[b][t] = pooled[b] . fc1_w[t] + fc1_b[t]   (32x4 outputs)
// ---------------------------------------------------------------------------
__global__ __launch_bounds__(128) void head(const int* __restrict__ pooled,
                                            const float* __restrict__ fc1w,
                                            const float* __restrict__ fc1b,
                                            float* __restrict__ out) {
    const int tid = threadIdx.x;        // 0..127
    const int b = tid >> 2;
    const int t = tid & 3;
    float acc = fc1b[t];
    #pragma unroll 4
    for (int oc = 0; oc < OC; ++oc) {
        acc += __int_as_float(pooled[b * OC + oc]) * fc1w[t * OC + oc];
    }
    out[b * TCO + t] = acc;
}

extern "C" void kernel_launch(void* const* d_in, const int* in_sizes, int n_in,
                              void* d_out, int out_size, void* d_ws, size_t ws_size,
                              hipStream_t stream) {
    const int*   tokens = (const int*)d_in[0];
    const float* K      = (const float*)d_in[1];
    const float* fc1w   = (const float*)d_in[2];
    const float* fc1b   = (const float*)d_in[3];
    float*       out    = (float*)d_out;

    const size_t ktBytes     = (size_t)KELEMS * sizeof(float);   // 76.8 MB
    const size_t pooledBytes = (size_t)NB * OC * sizeof(int);    // 16 KB

    const int ltiles = (L_OUT + 63) / 64;  // 40

    if (ws_size >= ktBytes + pooledBytes) {
        float* Kt  = (float*)d_ws;
        int* pooled = (int*)((char*)d_ws + ktBytes);
        hipMemsetAsync(pooled, 0, pooledBytes, stream);
        transpose_k<<<K_ROW / 16, 256, 0, stream>>>(K, Kt);  // 9375 blocks
        conv_max<<<dim3(ltiles, NB), 256, 0, stream>>>(tokens, Kt, pooled);
        head<<<1, 128, 0, stream>>>(pooled, fc1w, fc1b, out);
    } else {
        int* pooled = (int*)d_ws;
        hipMemsetAsync(pooled, 0, pooledBytes, stream);
        conv_max_fallback<<<dim3(ltiles, NB), 256, 0, stream>>>(tokens, K, pooled);
        head<<<1, 128, 0, stream>>>(pooled, fc1w, fc1b, out);
    }
}

// Round 6
// 141.301 us; speedup vs baseline: 1.5077x; 1.5077x over previous
//
#include <hip/hip_runtime.h>
#include <hip/hip_fp16.h>

#define OC 128
#define V_SZ 30000
#define KW 5
#define L_IN 2560              // 40*64
#define L_OUT (L_IN - KW + 1)  // 2556
#define NB 32
#define TCO 4
#define K_ROW (V_SZ * KW)      // 150000 floats per oc row
#define NI (V_SZ * KW)         // i = v*5+w index space

// ---------------------------------------------------------------------------
// Kernel A: transpose + fp16-convert  K[oc][i] (f32) -> Kth[i][oc] (f16).
// Tile: 48 i x 128 oc (3125 blocks exactly). Block 256.
// ---------------------------------------------------------------------------
__global__ __launch_bounds__(256) void transpose_k(const float* __restrict__ K,
                                                   __half* __restrict__ Kth) {
    __shared__ float lds[48 * 132];
    const int i0  = blockIdx.x * 48;
    const int tid = threadIdx.x;

    {
        const int ii4 = (tid & 3) * 4;
        const int ocr = tid >> 2;   // 0..63
        #pragma unroll
        for (int p = 0; p < 3; ++p) {
            #pragma unroll
            for (int r = 0; r < 2; ++r) {
                const int oc = r * 64 + ocr;
                const int ii = p * 16 + ii4;
                const float4 kv = *reinterpret_cast<const float4*>(
                    &K[(size_t)oc * K_ROW + i0 + ii]);
                lds[(ii + 0) * 132 + oc] = kv.x;
                lds[(ii + 1) * 132 + oc] = kv.y;
                lds[(ii + 2) * 132 + oc] = kv.z;
                lds[(ii + 3) * 132 + oc] = kv.w;
            }
        }
    }
    __syncthreads();
    {
        const int oc8 = (tid & 15) * 8;
        #pragma unroll
        for (int p = 0; p < 3; ++p) {
            const int i_loc = p * 16 + (tid >> 4);
            __half h[8];
            #pragma unroll
            for (int k = 0; k < 8; ++k) h[k] = __float2half(lds[i_loc * 132 + oc8 + k]);
            *reinterpret_cast<float4*>(&Kth[(size_t)(i0 + i_loc) * OC + oc8]) =
                *reinterpret_cast<const float4*>(h);
        }
    }
}

// ---------------------------------------------------------------------------
// Kernel B: conv + relu + max-pool from fp16 Kth.
// Grid: (80 l-tiles, 32 b) = 2560 blocks. Block 256 = 16 lgrps x 16 oc8-lanes.
// ---------------------------------------------------------------------------
__global__ __launch_bounds__(256) void conv_max(const int* __restrict__ tokens,
                                                const __half* __restrict__ Kth,
                                                int* __restrict__ pooled) {
    __shared__ int   ids[36];
    __shared__ float red[16 * 128];
    const int b   = blockIdx.y;
    const int l0  = blockIdx.x * 32;
    const int tid = threadIdx.x;

    if (tid < 36) {
        const int l = l0 + tid;
        ids[tid] = (l < L_IN) ? tokens[b * L_IN + l] : 0;
    }
    __syncthreads();

    const int lgrp = tid >> 4;        // 0..15
    const int oc8  = (tid & 15) * 8;  // 0..120

    float acc[8];
    #pragma unroll
    for (int k = 0; k < 8; ++k) acc[k] = 0.f;

    #pragma unroll
    for (int u = 0; u < 2; ++u) {
        const int li = u * 16 + lgrp;
        const int l  = l0 + li;
        if (l < L_OUT) {
            float s[8];
            #pragma unroll
            for (int k = 0; k < 8; ++k) s[k] = 0.f;
            #pragma unroll
            for (int w = 0; w < KW; ++w) {
                const int id = ids[li + w];
                const float4 raw = *reinterpret_cast<const float4*>(
                    &Kth[((size_t)id * KW + w) * OC + oc8]);
                const __half* h = reinterpret_cast<const __half*>(&raw);
                #pragma unroll
                for (int k = 0; k < 8; ++k) s[k] += __half2float(h[k]);
            }
            #pragma unroll
            for (int k = 0; k < 8; ++k) acc[k] = fmaxf(acc[k], s[k]);
        }
    }

    #pragma unroll
    for (int k = 0; k < 8; ++k) red[lgrp * 128 + oc8 + k] = acc[k];
    __syncthreads();

    if (tid < 128) {
        float m = red[tid];
        #pragma unroll
        for (int g = 1; g < 16; ++g) m = fmaxf(m, red[g * 128 + tid]);
        atomicMax(&pooled[b * OC + tid], __float_as_int(m));
    }
}

// ---------------------------------------------------------------------------
// Fallback (ws too small): gather from original f32 layout.
// ---------------------------------------------------------------------------
__global__ __launch_bounds__(256) void conv_max_fallback(const int* __restrict__ tokens,
                                                         const float* __restrict__ K,
                                                         int* __restrict__ pooled) {
    const int b   = blockIdx.y;
    const int l0  = blockIdx.x * 64;
    const int tid = threadIdx.x;

    __shared__ int ids[64 + KW - 1];
    if (tid < 64 + KW - 1) {
        const int l = l0 + tid;
        ids[tid] = (l < L_IN) ? tokens[b * L_IN + l] : 0;
    }
    __syncthreads();

    const int oc   = tid & 127;
    const int half = tid >> 7;
    float m = 0.f;
    for (int u = 0; u < 32; ++u) {
        const int li = u * 2 + half;
        const int l  = l0 + li;
        if (l < L_OUT) {
            float s = 0.f;
            #pragma unroll
            for (int w = 0; w < KW; ++w)
                s += K[(size_t)oc * K_ROW + ids[li + w] * KW + w];
            m = fmaxf(m, s);
        }
    }
    atomicMax(&pooled[b * OC + oc], __float_as_int(m));
}

// ---------------------------------------------------------------------------
// Kernel C: out[b][t] = pooled[b] . fc1_w[t] + fc1_b[t]
// ---------------------------------------------------------------------------
__global__ __launch_bounds__(128) void head(const int* __restrict__ pooled,
                                            const float* __restrict__ fc1w,
                                            const float* __restrict__ fc1b,
                                            float* __restrict__ out) {
    const int tid = threadIdx.x;
    const int b = tid >> 2;
    const int t = tid & 3;
    float acc = fc1b[t];
    #pragma unroll 4
    for (int oc = 0; oc < OC; ++oc)
        acc += __int_as_float(pooled[b * OC + oc]) * fc1w[t * OC + oc];
    out[b * TCO + t] = acc;
}

extern "C" void kernel_launch(void* const* d_in, const int* in_sizes, int n_in,
                              void* d_out, int out_size, void* d_ws, size_t ws_size,
                              hipStream_t stream) {
    const int*   tokens = (const int*)d_in[0];
    const float* K      = (const float*)d_in[1];
    const float* fc1w   = (const float*)d_in[2];
    const float* fc1b   = (const float*)d_in[3];
    float*       out    = (float*)d_out;

    const size_t kthBytes    = (size_t)NI * OC * sizeof(__half);  // 38.4 MB
    const size_t pooledBytes = (size_t)NB * OC * sizeof(int);     // 16 KB

    if (ws_size >= kthBytes + pooledBytes) {
        __half* Kth  = (__half*)d_ws;
        int* pooled  = (int*)((char*)d_ws + kthBytes);
        hipMemsetAsync(pooled, 0, pooledBytes, stream);
        transpose_k<<<NI / 48, 256, 0, stream>>>(K, Kth);               // 3125 blocks
        conv_max<<<dim3((L_OUT + 31) / 32, NB), 256, 0, stream>>>(tokens, Kth, pooled);
        head<<<1, 128, 0, stream>>>(pooled, fc1w, fc1b, out);
    } else {
        int* pooled = (int*)d_ws;
        hipMemsetAsync(pooled, 0, pooledBytes, stream);
        conv_max_fallback<<<dim3((L_OUT + 63) / 64, NB), 256, 0, stream>>>(tokens, K, pooled);
        head<<<1, 128, 0, stream>>>(pooled, fc1w, fc1b, out);
    }
}